// Round 4
// baseline (18991.615 us; speedup 1.0000x reference)
//
#include <hip/hip_runtime.h>
#include <hip/hip_bf16.h>
#include <math.h>

// Problem dims (fixed by reference)
#define BATCH 4096
#define SEQ   512
#define FDIM  128    // F
#define DDIM  256    // D = 2F
#define KG    384    // F + D  (gates K)
#define NG    1024   // 4D     (gates N)

typedef __bf16 bf16x8 __attribute__((ext_vector_type(8)));
typedef float  f32x4  __attribute__((ext_vector_type(4)));

__device__ __forceinline__ f32x4 mfma16(bf16x8 a, bf16x8 b, f32x4 c) {
    return __builtin_amdgcn_mfma_f32_16x16x32_bf16(a, b, c, 0, 0, 0);
}

__device__ __forceinline__ float rcp_(float x) { return __builtin_amdgcn_rcpf(x); }
__device__ __forceinline__ float sigmoid_(float x) { return rcp_(1.0f + __expf(-x)); }
__device__ __forceinline__ float tanh_(float x) {
    float e = __expf(-2.0f * fabsf(x));
    float t = 1.0f - 2.0f * e * rcp_(1.0f + e);
    return copysignf(t, x);
}
// Abramowitz-Stegun 7.1.26, |err| < 1.5e-7
__device__ __forceinline__ float erf_(float x) {
    float ax = fabsf(x);
    float t  = rcp_(fmaf(0.3275911f, ax, 1.0f));
    float y  = t * fmaf(t, fmaf(t, fmaf(t, fmaf(t, 1.061405429f, -1.453152027f),
                                        1.421413741f), -0.284496736f), 0.254829592f);
    float r  = 1.0f - y * __expf(-ax * ax);
    return copysignf(r, x);
}
__device__ __forceinline__ float gelu_erf(float v) {
    return 0.5f * v * (1.0f + erf_(v * 0.70710678118654752f));
}

// ---------------- prep: pack weights to bf16, combine biases ----------------
__global__ void prep_weights(const float* __restrict__ w_ih, const float* __restrict__ w_hh,
                             const float* __restrict__ b_ih, const float* __restrict__ b_hh,
                             const float* __restrict__ out_w, const float* __restrict__ z_w,
                             __bf16* __restrict__ Wg, __bf16* __restrict__ Wout,
                             __bf16* __restrict__ Wz, float* __restrict__ bg)
{
    int i = blockIdx.x * blockDim.x + threadIdx.x;
    if (i < NG * KG) {
        int n = i / KG, k = i - n * KG;
        float v = (k < FDIM) ? w_ih[n * FDIM + k] : w_hh[n * DDIM + (k - FDIM)];
        Wg[i] = (__bf16)v;
    }
    if (i < FDIM * DDIM) Wout[i] = (__bf16)out_w[i];
    if (i < DDIM * FDIM) Wz[i]   = (__bf16)z_w[i];
    if (i < NG)          bg[i]   = b_ih[i] + b_hh[i];
}

// ---------------- preamble MLP ----------------
template<int K, int N, int ACT>
__global__ void rowmlp(const float* __restrict__ x, const float* __restrict__ W,
                       const float* __restrict__ bias, float* __restrict__ y)
{
    __shared__ float xr[K];
    int m = blockIdx.x;
    for (int k = threadIdx.x; k < K; k += blockDim.x) xr[k] = x[(size_t)m * K + k];
    __syncthreads();
    for (int n = threadIdx.x; n < N; n += blockDim.x) {
        const float* wr = W + (size_t)n * K;
        float s = bias[n];
        #pragma unroll 8
        for (int k = 0; k < K; ++k) s += xr[k] * wr[k];
        if (ACT) s = gelu_erf(s);
        y[(size_t)m * N + n] = s;
    }
}

// raw barrier without vmcnt drain: LDS writes visible, vmem prefetch stays in flight
__device__ __forceinline__ void bar_lds() {
    asm volatile("s_waitcnt lgkmcnt(0)" ::: "memory");
    __builtin_amdgcn_sched_barrier(0);
    __builtin_amdgcn_s_barrier();
    __builtin_amdgcn_sched_barrier(0);
}

// ---------------- persistent RNN scan: 1 WG/CU, 16 batch rows each ----------------
// A-frag LDS block layout: element (r,k) at byte ((k>>3)*16 + r)*16 + (k&7)*2.
// Gates K-loop: 12 kt weight batches streamed from L2 with PLAIN register loads
// (L2-resident, R2-proven) through a 4-deep software pipeline bb[4][8].
// Next step's first 4 batches are issued during the cell/out/z tail and stay in
// flight across the lgkm-only barriers. Wout + Wz stay VGPR-resident.
__global__ __launch_bounds__(512, 2)
void rnn_main(const float* __restrict__ eps,
              const __bf16* __restrict__ Wg, const float* __restrict__ bg,
              const __bf16* __restrict__ Wout, const float* __restrict__ ob,
              const __bf16* __restrict__ Wz, const float* __restrict__ zb,
              const float* __restrict__ x0, const float* __restrict__ h0,
              float* __restrict__ out)
{
    extern __shared__ __align__(16) char smem[];
    __bf16* xbuf  = (__bf16*)smem;            // 4 KB   x: 16 kgroups
    __bf16* hbufA = (__bf16*)(smem + 4096);   // 8 KB   h double-buffer
    __bf16* hbufB = (__bf16*)(smem + 12288);  // 8 KB
    __bf16* gbuf  = (__bf16*)(smem + 20480);  // 4 KB   gelu(out)

    const int tid  = threadIdx.x;
    const int wv   = tid >> 6;
    const int lane = tid & 63;
    const int lo   = lane & 15;
    const int hi   = lane >> 4;
    const int row0 = blockIdx.x * 16;
    const int abase = (hi * 16 + lo) * 16;    // A-frag byte offset within kt-block

    // ---- init activations ----
    for (int e = tid; e < 16 * 128; e += 512) {
        int r = e >> 7, k = e & 127;
        xbuf[(((k >> 3) << 4) + r) * 8 + (k & 7)] = (__bf16)x0[(size_t)(row0 + r) * 128 + k];
    }
    for (int e = tid; e < 16 * 256; e += 512) {
        int r = e >> 8, k = e & 255;
        hbufA[(((k >> 3) << 4) + r) * 8 + (k & 7)] = (__bf16)h0[(size_t)(row0 + r) * 256 + k];
    }
    float c[2][4];
    #pragma unroll
    for (int p = 0; p < 2; ++p)
        #pragma unroll
        for (int j = 0; j < 4; ++j)
            c[p][j] = tanh_(h0[(size_t)(row0 + hi * 4 + j) * 256 + (2 * wv + p) * 16 + lo]);

    // ---- per-q weight row base pointers + biases ----
    const __bf16* wgbase[8];
    float biasq[8];
    #pragma unroll
    for (int q = 0; q < 8; ++q) {
        int tile = (q >> 1) * 16 + 2 * wv + (q & 1);
        wgbase[q] = Wg + (size_t)(tile * 16 + lo) * KG + hi * 8;
        biasq[q]  = bg[tile * 16 + lo];
    }
    const float bo  = ob[wv * 16 + lo];
    const float bmu = zb[wv * 16 + lo];
    const float bls = zb[128 + wv * 16 + lo];

    // ---- resident weights: VGPRs ----
    bf16x8 wout[8];
    #pragma unroll
    for (int kt = 0; kt < 8; ++kt)
        wout[kt] = *(const bf16x8*)(Wout + (size_t)(wv * 16 + lo) * 256 + kt * 32 + hi * 8);
    bf16x8 wz0[4], wz1[4];
    #pragma unroll
    for (int kt = 0; kt < 4; ++kt) {
        wz0[kt] = *(const bf16x8*)(Wz + (size_t)(wv * 16 + lo) * 128 + kt * 32 + hi * 8);
        wz1[kt] = *(const bf16x8*)(Wz + (size_t)((8 + wv) * 16 + lo) * 128 + kt * 32 + hi * 8);
    }

    // ---- 4-deep weight pipeline: prologue loads kt 0..3 ----
    bf16x8 bb[4][8];
    #pragma unroll
    for (int s = 0; s < 4; ++s)
        #pragma unroll
        for (int q = 0; q < 8; ++q)
            bb[s][q] = *(const bf16x8*)(wgbase[q] + s * 32);

    __syncthreads();   // init-phase LDS writes visible (one-time full drain is fine)

    __bf16* hc = hbufA;
    __bf16* hn = hbufB;

    for (int t = 0; t < SEQ; ++t) {
        // eps loads issued first; consumed at step end (compiler-managed wait)
        float ev[4];
        #pragma unroll
        for (int j = 0; j < 4; ++j)
            ev[j] = eps[((size_t)t * BATCH + row0 + hi * 4 + j) * 128 + wv * 16 + lo];

        // ---- gates = [x|h] @ Wg^T + b ----
        f32x4 acc[8];
        #pragma unroll
        for (int q = 0; q < 8; ++q) acc[q] = (f32x4){biasq[q], biasq[q], biasq[q], biasq[q]};

        #pragma unroll
        for (int i = 0; i < 12; ++i) {
            const char* aptr = (i < 4) ? ((const char*)xbuf + i * 1024)
                                       : ((const char*)hc + (i - 4) * 1024);
            bf16x8 a = *(const bf16x8*)(aptr + abase);
            #pragma unroll
            for (int q = 0; q < 8; ++q)
                acc[q] = mfma16(a, bb[i & 3][q], acc[q]);
            if (i < 8) {            // refill slot with batch i+4 (scheduler renames)
                #pragma unroll
                for (int q = 0; q < 8; ++q)
                    bb[i & 3][q] = *(const bf16x8*)(wgbase[q] + (i + 4) * 32);
            }
        }
        // issue next step's kt 0..3 now; they ride across the tail + barriers
        #pragma unroll
        for (int s = 0; s < 4; ++s)
            #pragma unroll
            for (int q = 0; q < 8; ++q)
                bb[s][q] = *(const bf16x8*)(wgbase[q] + s * 32);

        // ---- lane-local LSTM cell (acc order: i0 i1 f0 f1 g0 g1 o0 o1) ----
        #pragma unroll
        for (int p = 0; p < 2; ++p)
            #pragma unroll
            for (int j = 0; j < 4; ++j) {
                float iv = sigmoid_(acc[0 + p][j]);
                float fv = sigmoid_(acc[2 + p][j]);
                float gv = tanh_(acc[4 + p][j]);
                float ov = sigmoid_(acc[6 + p][j]);
                float cn = fv * c[p][j] + iv * gv;
                c[p][j] = cn;
                float hv = ov * tanh_(cn);
                int d = (2 * wv + p) * 16 + lo, r = hi * 4 + j;
                hn[(((d >> 3) << 4) + r) * 8 + (d & 7)] = (__bf16)hv;
            }
        bar_lds();   // (1) new h visible (lgkm only; weight prefetch stays in flight)

        // ---- out = h @ Wout^T + ob (load-free) ----
        f32x4 ao0 = (f32x4){bo, bo, bo, bo};
        f32x4 ao1 = (f32x4){0.f, 0.f, 0.f, 0.f};
        #pragma unroll
        for (int kt = 0; kt < 4; ++kt) {
            bf16x8 a0 = *(const bf16x8*)((const char*)hn + (2 * kt) * 1024 + abase);
            bf16x8 a1 = *(const bf16x8*)((const char*)hn + (2 * kt + 1) * 1024 + abase);
            ao0 = mfma16(a0, wout[2 * kt], ao0);
            ao1 = mfma16(a1, wout[2 * kt + 1], ao1);
        }
        #pragma unroll
        for (int j = 0; j < 4; ++j) {
            int d = wv * 16 + lo, r = hi * 4 + j;
            gbuf[(((d >> 3) << 4) + r) * 8 + (d & 7)] = (__bf16)gelu_erf(ao0[j] + ao1[j]);
        }
        bar_lds();   // (2) gelu(out) visible

        // ---- z = gelu(out) @ Wz^T + zb (load-free) ----
        f32x4 amu = (f32x4){bmu, bmu, bmu, bmu};
        f32x4 als = (f32x4){bls, bls, bls, bls};
        #pragma unroll
        for (int kt = 0; kt < 4; ++kt) {
            bf16x8 a = *(const bf16x8*)((const char*)gbuf + kt * 1024 + abase);
            amu = mfma16(a, wz0[kt], amu);
            als = mfma16(a, wz1[kt], als);
        }
        #pragma unroll
        for (int j = 0; j < 4; ++j) {
            float smp = amu[j] + __expf(als[j]) * ev[j];
            int d = wv * 16 + lo, r = hi * 4 + j;
            xbuf[(((d >> 3) << 4) + r) * 8 + (d & 7)] = (__bf16)smp;
            out[(size_t)(row0 + r) * (SEQ * 128) + (size_t)t * 128 + d] = smp;
        }
        bar_lds();   // (3) xbuf ready for next step

        __bf16* tmp = hc; hc = hn; hn = tmp;
    }
}

// ---------------- launch ----------------
extern "C" void kernel_launch(void* const* d_in, const int* in_sizes, int n_in,
                              void* d_out, int out_size, void* d_ws, size_t ws_size,
                              hipStream_t stream)
{
    const float* noise = (const float*)d_in[0];
    const float* eps   = (const float*)d_in[1];
    const float* w1 = (const float*)d_in[2];  const float* b1 = (const float*)d_in[3];
    const float* w2 = (const float*)d_in[4];  const float* b2 = (const float*)d_in[5];
    const float* w3 = (const float*)d_in[6];  const float* b3 = (const float*)d_in[7];
    const float* hw = (const float*)d_in[8];  const float* hb = (const float*)d_in[9];
    const float* wih = (const float*)d_in[10]; const float* bih = (const float*)d_in[11];
    const float* whh = (const float*)d_in[12]; const float* bhh = (const float*)d_in[13];
    const float* ow = (const float*)d_in[14]; const float* ob = (const float*)d_in[15];
    const float* zw = (const float*)d_in[16]; const float* zb = (const float*)d_in[17];
    float* out = (float*)d_out;

    char* ws = (char*)d_ws;
    __bf16* Wg   = (__bf16*)(ws);                         // 786432 B
    __bf16* Wout = (__bf16*)(ws + 786432);                // 65536 B
    __bf16* Wz   = (__bf16*)(ws + 851968);                // 65536 B
    float*  bg   = (float*) (ws + 917504);                // 4096 B
    float*  t0   = (float*) (ws + 921600);                // 2 MiB
    float*  t1   = (float*) (ws + 921600 + 2097152);      // 2 MiB
    float*  hid  = (float*) (ws + 921600 + 2 * 2097152);  // 4 MiB

    prep_weights<<<1536, 256, 0, stream>>>(wih, whh, bih, bhh, ow, zw, Wg, Wout, Wz, bg);

    rowmlp<128, 128, 1><<<4096, 128, 0, stream>>>(noise, w1, b1, t0);
    rowmlp<128, 128, 1><<<4096, 128, 0, stream>>>(t0, w2, b2, t1);
    rowmlp<128, 128, 0><<<4096, 128, 0, stream>>>(t1, w3, b3, t0);   // inputs
    rowmlp<128, 256, 0><<<4096, 256, 0, stream>>>(t0, hw, hb, hid);  // hidden

    // dynamic LDS: activations only (24 KB)
    rnn_main<<<256, 512, 24576, stream>>>(eps, Wg, bg, Wout, ob, Wz, zb, t0, hid, out);
}

// Round 5
// 12973.808 us; speedup vs baseline: 1.4638x; 1.4638x over previous
//
#include <hip/hip_runtime.h>
#include <hip/hip_bf16.h>
#include <math.h>

// Problem dims (fixed by reference)
#define BATCH 4096
#define SEQ   512
#define FDIM  128    // F
#define DDIM  256    // D = 2F
#define KG    384    // F + D  (gates K)
#define NG    1024   // 4D     (gates N)

typedef __bf16 bf16x8 __attribute__((ext_vector_type(8)));
typedef float  f32x4  __attribute__((ext_vector_type(4)));

__device__ __forceinline__ f32x4 mfma16(bf16x8 a, bf16x8 b, f32x4 c) {
    return __builtin_amdgcn_mfma_f32_16x16x32_bf16(a, b, c, 0, 0, 0);
}

__device__ __forceinline__ float rcp_(float x) { return __builtin_amdgcn_rcpf(x); }
__device__ __forceinline__ float sigmoid_(float x) { return rcp_(1.0f + __expf(-x)); }
__device__ __forceinline__ float tanh_(float x) {
    float e = __expf(-2.0f * fabsf(x));
    float t = 1.0f - 2.0f * e * rcp_(1.0f + e);
    return copysignf(t, x);
}
// Abramowitz-Stegun 7.1.26, |err| < 1.5e-7
__device__ __forceinline__ float erf_(float x) {
    float ax = fabsf(x);
    float t  = rcp_(fmaf(0.3275911f, ax, 1.0f));
    float y  = t * fmaf(t, fmaf(t, fmaf(t, fmaf(t, 1.061405429f, -1.453152027f),
                                        1.421413741f), -0.284496736f), 0.254829592f);
    float r  = 1.0f - y * __expf(-ax * ax);
    return copysignf(r, x);
}
__device__ __forceinline__ float gelu_erf(float v) {
    return 0.5f * v * (1.0f + erf_(v * 0.70710678118654752f));
}

// ---------------- prep: pack weights to bf16, combine biases ----------------
__global__ void prep_weights(const float* __restrict__ w_ih, const float* __restrict__ w_hh,
                             const float* __restrict__ b_ih, const float* __restrict__ b_hh,
                             const float* __restrict__ out_w, const float* __restrict__ z_w,
                             __bf16* __restrict__ Wg, __bf16* __restrict__ Wout,
                             __bf16* __restrict__ Wz, float* __restrict__ bg)
{
    int i = blockIdx.x * blockDim.x + threadIdx.x;
    if (i < NG * KG) {
        int n = i / KG, k = i - n * KG;
        float v = (k < FDIM) ? w_ih[n * FDIM + k] : w_hh[n * DDIM + (k - FDIM)];
        Wg[i] = (__bf16)v;
    }
    if (i < FDIM * DDIM) Wout[i] = (__bf16)out_w[i];
    if (i < DDIM * FDIM) Wz[i]   = (__bf16)z_w[i];
    if (i < NG)          bg[i]   = b_ih[i] + b_hh[i];
}

// ---------------- preamble MLP ----------------
template<int K, int N, int ACT>
__global__ void rowmlp(const float* __restrict__ x, const float* __restrict__ W,
                       const float* __restrict__ bias, float* __restrict__ y)
{
    __shared__ float xr[K];
    int m = blockIdx.x;
    for (int k = threadIdx.x; k < K; k += blockDim.x) xr[k] = x[(size_t)m * K + k];
    __syncthreads();
    for (int n = threadIdx.x; n < N; n += blockDim.x) {
        const float* wr = W + (size_t)n * K;
        float s = bias[n];
        #pragma unroll 8
        for (int k = 0; k < K; ++k) s += xr[k] * wr[k];
        if (ACT) s = gelu_erf(s);
        y[(size_t)m * N + n] = s;
    }
}

// ---------------- persistent RNN scan: 1 WG/CU (1024 thr, 16 waves), 16 rows ----------------
// A-frag LDS block layout: element (r,k) at byte ((k>>3)*16 + r)*16 + (k&7)*2.
// Wave w (0..15) owns gate tiles {q*16+w : q=0..3} -> lane-local i,f,g,o for col w*16+lo.
// Weights: Wg kt=8,9 LDS-resident (128 KB); kt 0..7,10,11 streamed as plain register
// loads near use (R2-proven L2-resident idiom); full-drain __syncthreads only.
// Tail: out phase on waves 0..7; z phase 16 tiles on 16 waves (mu: w<8, logsigma: w>=8),
// logsigma exchanged through the dead old-h LDS buffer.
__global__ __launch_bounds__(1024, 4)
void rnn_main(const float* __restrict__ eps,
              const __bf16* __restrict__ Wg, const float* __restrict__ bg,
              const __bf16* __restrict__ Wout, const float* __restrict__ ob,
              const __bf16* __restrict__ Wz, const float* __restrict__ zb,
              const float* __restrict__ x0, const float* __restrict__ h0,
              float* __restrict__ out)
{
    extern __shared__ __align__(16) char smem[];
    __bf16* xbuf  = (__bf16*)smem;            // 4 KB   x: 4 kt-blocks
    __bf16* hbufA = (__bf16*)(smem + 4096);   // 8 KB   h double-buffer (8 kt-blocks)
    __bf16* hbufB = (__bf16*)(smem + 12288);  // 8 KB
    __bf16* gbuf  = (__bf16*)(smem + 20480);  // 4 KB   gelu(out)
    char*   wlds  = smem + 24576;             // 128 KB: [(kt2*16+w)*4+q]*1024 + lane*16

    const int tid  = threadIdx.x;
    const int w    = tid >> 6;      // wave 0..15
    const int lane = tid & 63;
    const int lo   = lane & 15;
    const int hi   = lane >> 4;
    const int row0 = blockIdx.x * 16;
    const int abase = (hi * 16 + lo) * 16;    // A-frag byte offset within kt-block

    // ---- init activations ----
    for (int e = tid; e < 16 * 128; e += 1024) {
        int r = e >> 7, k = e & 127;
        xbuf[(((k >> 3) << 4) + r) * 8 + (k & 7)] = (__bf16)x0[(size_t)(row0 + r) * 128 + k];
    }
    for (int e = tid; e < 16 * 256; e += 1024) {
        int r = e >> 8, k = e & 255;
        hbufA[(((k >> 3) << 4) + r) * 8 + (k & 7)] = (__bf16)h0[(size_t)(row0 + r) * 256 + k];
    }
    // c state: rows hi*4+j, col d = w*16+lo
    float c[4];
    #pragma unroll
    for (int j = 0; j < 4; ++j)
        c[j] = tanh_(h0[(size_t)(row0 + hi * 4 + j) * 256 + w * 16 + lo]);

    // ---- per-q weight row base pointers + biases (tile = q*16 + w) ----
    const __bf16* wgbase[4];
    float biasq[4];
    #pragma unroll
    for (int q = 0; q < 4; ++q) {
        int tile = q * 16 + w;
        wgbase[q] = Wg + (size_t)(tile * 16 + lo) * KG + hi * 8;
        biasq[q]  = bg[tile * 16 + lo];
    }
    const float bo = (w < 8) ? ob[w * 16 + lo] : 0.0f;
    const float bz = zb[w * 16 + lo];   // mu bias for w<8, logsigma bias for w>=8

    // ---- LDS-resident Wg kt=8,9 ----
    #pragma unroll
    for (int kt2 = 0; kt2 < 2; ++kt2)
        #pragma unroll
        for (int q = 0; q < 4; ++q) {
            bf16x8 v = *(const bf16x8*)(wgbase[q] + (8 + kt2) * 32);
            *(bf16x8*)(wlds + (size_t)((kt2 * 16 + w) * 4 + q) * 1024 + lane * 16) = v;
        }

    __syncthreads();

    __bf16* hc = hbufA;
    __bf16* hn = hbufB;

    for (int t = 0; t < SEQ; ++t) {
        // eps for this step (waves 0..7 only; consumed at step end)
        float ev[4] = {0.f, 0.f, 0.f, 0.f};
        if (w < 8) {
            #pragma unroll
            for (int j = 0; j < 4; ++j)
                ev[j] = eps[((size_t)t * BATCH + row0 + hi * 4 + j) * 128 + w * 16 + lo];
        }

        // ---- gates = [x|h] @ Wg^T + b : kt order 8,9 (LDS) then streamed ----
        f32x4 acc[4];
        #pragma unroll
        for (int q = 0; q < 4; ++q) acc[q] = (f32x4){biasq[q], biasq[q], biasq[q], biasq[q]};

        #pragma unroll
        for (int kt2 = 0; kt2 < 2; ++kt2) {          // kt 8,9 from LDS (start instantly)
            bf16x8 a = *(const bf16x8*)((const char*)hc + (4 + kt2) * 1024 + abase);
            #pragma unroll
            for (int q = 0; q < 4; ++q) {
                bf16x8 b = *(const bf16x8*)(wlds + (size_t)((kt2 * 16 + w) * 4 + q) * 1024 + lane * 16);
                acc[q] = mfma16(a, b, acc[q]);
            }
        }
        #pragma unroll 2
        for (int kt = 0; kt < 4; ++kt) {             // x part (streamed)
            bf16x8 a = *(const bf16x8*)((const char*)xbuf + kt * 1024 + abase);
            #pragma unroll
            for (int q = 0; q < 4; ++q) {
                bf16x8 b = *(const bf16x8*)(wgbase[q] + kt * 32);
                acc[q] = mfma16(a, b, acc[q]);
            }
        }
        #pragma unroll 2
        for (int kt = 4; kt < 8; ++kt) {             // h part kt 4..7 (streamed)
            bf16x8 a = *(const bf16x8*)((const char*)hc + (kt - 4) * 1024 + abase);
            #pragma unroll
            for (int q = 0; q < 4; ++q) {
                bf16x8 b = *(const bf16x8*)(wgbase[q] + kt * 32);
                acc[q] = mfma16(a, b, acc[q]);
            }
        }
        #pragma unroll
        for (int kt = 10; kt < 12; ++kt) {           // h part kt 10,11 (streamed)
            bf16x8 a = *(const bf16x8*)((const char*)hc + (kt - 4) * 1024 + abase);
            #pragma unroll
            for (int q = 0; q < 4; ++q) {
                bf16x8 b = *(const bf16x8*)(wgbase[q] + kt * 32);
                acc[q] = mfma16(a, b, acc[q]);
            }
        }

        // issue wout/wz loads now: they retire under the cell VALU work
        bf16x8 wo[8];
        if (w < 8) {
            #pragma unroll
            for (int kt = 0; kt < 8; ++kt)
                wo[kt] = *(const bf16x8*)(Wout + (size_t)(w * 16 + lo) * 256 + kt * 32 + hi * 8);
        }
        bf16x8 wzv[4];
        #pragma unroll
        for (int kt = 0; kt < 4; ++kt)
            wzv[kt] = *(const bf16x8*)(Wz + (size_t)(w * 16 + lo) * 128 + kt * 32 + hi * 8);

        // ---- lane-local LSTM cell (acc: q=0 i, 1 f, 2 g, 3 o) ----
        #pragma unroll
        for (int j = 0; j < 4; ++j) {
            float iv = sigmoid_(acc[0][j]);
            float fv = sigmoid_(acc[1][j]);
            float gv = tanh_(acc[2][j]);
            float ov = sigmoid_(acc[3][j]);
            float cn = fv * c[j] + iv * gv;
            c[j] = cn;
            float hv = ov * tanh_(cn);
            int d = w * 16 + lo, r = hi * 4 + j;
            hn[(((d >> 3) << 4) + r) * 8 + (d & 7)] = (__bf16)hv;
        }
        __syncthreads();   // (1) new h visible; hc is now dead (reused as pls below)

        // ---- out = h @ Wout^T + ob (waves 0..7) ----
        if (w < 8) {
            f32x4 ao = (f32x4){bo, bo, bo, bo};
            #pragma unroll
            for (int kt = 0; kt < 8; ++kt) {
                bf16x8 a = *(const bf16x8*)((const char*)hn + kt * 1024 + abase);
                ao = mfma16(a, wo[kt], ao);
            }
            #pragma unroll
            for (int j = 0; j < 4; ++j) {
                int d = w * 16 + lo, r = hi * 4 + j;
                gbuf[(((d >> 3) << 4) + r) * 8 + (d & 7)] = (__bf16)gelu_erf(ao[j]);
            }
        }
        __syncthreads();   // (2) gelu(out) visible

        // ---- z: wave w<8 -> mu tile w; wave w>=8 -> logsigma tile w-8 ----
        f32x4 az = (f32x4){bz, bz, bz, bz};
        #pragma unroll
        for (int kt = 0; kt < 4; ++kt) {
            bf16x8 a = *(const bf16x8*)((const char*)gbuf + kt * 1024 + abase);
            az = mfma16(a, wzv[kt], az);
        }
        if (w >= 8) {                       // publish logsigma through dead hc buffer
            float* pls = (float*)hc;
            #pragma unroll
            for (int j = 0; j < 4; ++j)
                pls[(w - 8) * 256 + (hi * 4 + j) * 16 + lo] = az[j];
        }
        __syncthreads();   // (3) logsigma visible

        if (w < 8) {
            const float* pls = (const float*)hc;
            #pragma unroll
            for (int j = 0; j < 4; ++j) {
                float ls  = pls[w * 256 + (hi * 4 + j) * 16 + lo];
                float smp = az[j] + __expf(ls) * ev[j];
                int d = w * 16 + lo, r = hi * 4 + j;
                xbuf[(((d >> 3) << 4) + r) * 8 + (d & 7)] = (__bf16)smp;
                out[(size_t)(row0 + r) * (SEQ * 128) + (size_t)t * 128 + d] = smp;
            }
        }
        __syncthreads();   // (4) xbuf ready for next step

        __bf16* tmp = hc; hc = hn; hn = tmp;
    }
}

// ---------------- launch ----------------
extern "C" void kernel_launch(void* const* d_in, const int* in_sizes, int n_in,
                              void* d_out, int out_size, void* d_ws, size_t ws_size,
                              hipStream_t stream)
{
    const float* noise = (const float*)d_in[0];
    const float* eps   = (const float*)d_in[1];
    const float* w1 = (const float*)d_in[2];  const float* b1 = (const float*)d_in[3];
    const float* w2 = (const float*)d_in[4];  const float* b2 = (const float*)d_in[5];
    const float* w3 = (const float*)d_in[6];  const float* b3 = (const float*)d_in[7];
    const float* hw = (const float*)d_in[8];  const float* hb = (const float*)d_in[9];
    const float* wih = (const float*)d_in[10]; const float* bih = (const float*)d_in[11];
    const float* whh = (const float*)d_in[12]; const float* bhh = (const float*)d_in[13];
    const float* ow = (const float*)d_in[14]; const float* ob = (const float*)d_in[15];
    const float* zw = (const float*)d_in[16]; const float* zb = (const float*)d_in[17];
    float* out = (float*)d_out;

    char* ws = (char*)d_ws;
    __bf16* Wg   = (__bf16*)(ws);                         // 786432 B
    __bf16* Wout = (__bf16*)(ws + 786432);                // 65536 B
    __bf16* Wz   = (__bf16*)(ws + 851968);                // 65536 B
    float*  bg   = (float*) (ws + 917504);                // 4096 B
    float*  t0   = (float*) (ws + 921600);                // 2 MiB
    float*  t1   = (float*) (ws + 921600 + 2097152);      // 2 MiB
    float*  hid  = (float*) (ws + 921600 + 2 * 2097152);  // 4 MiB

    prep_weights<<<1536, 256, 0, stream>>>(wih, whh, bih, bhh, ow, zw, Wg, Wout, Wz, bg);

    rowmlp<128, 128, 1><<<4096, 128, 0, stream>>>(noise, w1, b1, t0);
    rowmlp<128, 128, 1><<<4096, 128, 0, stream>>>(t0, w2, b2, t1);
    rowmlp<128, 128, 0><<<4096, 128, 0, stream>>>(t1, w3, b3, t0);   // inputs
    rowmlp<128, 256, 0><<<4096, 256, 0, stream>>>(t0, hw, hb, hid);  // hidden

    // dynamic LDS: 24576 B activations + 131072 B resident Wg kt=8,9
    rnn_main<<<256, 1024, 155648, stream>>>(eps, Wg, bg, Wout, ob, Wz, zb, t0, hid, out);
}

// Round 6
// 11725.526 us; speedup vs baseline: 1.6197x; 1.1065x over previous
//
#include <hip/hip_runtime.h>
#include <hip/hip_bf16.h>
#include <math.h>

// Problem dims (fixed by reference)
#define BATCH 4096
#define SEQ   512
#define FDIM  128    // F
#define DDIM  256    // D = 2F
#define KG    384    // F + D  (gates K)
#define NG    1024   // 4D     (gates N)

typedef __bf16 bf16x8 __attribute__((ext_vector_type(8)));
typedef float  f32x4  __attribute__((ext_vector_type(4)));

__device__ __forceinline__ f32x4 mfma16(bf16x8 a, bf16x8 b, f32x4 c) {
    return __builtin_amdgcn_mfma_f32_16x16x32_bf16(a, b, c, 0, 0, 0);
}

__device__ __forceinline__ float rcp_(float x) { return __builtin_amdgcn_rcpf(x); }
__device__ __forceinline__ float sigmoid_(float x) { return rcp_(1.0f + __expf(-x)); }
__device__ __forceinline__ float tanh_(float x) {
    float e = __expf(-2.0f * fabsf(x));
    float t = 1.0f - 2.0f * e * rcp_(1.0f + e);
    return copysignf(t, x);
}
// Abramowitz-Stegun 7.1.26, |err| < 1.5e-7
__device__ __forceinline__ float erf_(float x) {
    float ax = fabsf(x);
    float t  = rcp_(fmaf(0.3275911f, ax, 1.0f));
    float y  = t * fmaf(t, fmaf(t, fmaf(t, fmaf(t, 1.061405429f, -1.453152027f),
                                        1.421413741f), -0.284496736f), 0.254829592f);
    float r  = 1.0f - y * __expf(-ax * ax);
    return copysignf(r, x);
}
__device__ __forceinline__ float gelu_erf(float v) {
    return 0.5f * v * (1.0f + erf_(v * 0.70710678118654752f));
}

// ---------------- prep: pack weights to bf16, combine biases ----------------
__global__ void prep_weights(const float* __restrict__ w_ih, const float* __restrict__ w_hh,
                             const float* __restrict__ b_ih, const float* __restrict__ b_hh,
                             const float* __restrict__ out_w, const float* __restrict__ z_w,
                             __bf16* __restrict__ Wg, __bf16* __restrict__ Wout,
                             __bf16* __restrict__ Wz, float* __restrict__ bg)
{
    int i = blockIdx.x * blockDim.x + threadIdx.x;
    if (i < NG * KG) {
        int n = i / KG, k = i - n * KG;
        float v = (k < FDIM) ? w_ih[n * FDIM + k] : w_hh[n * DDIM + (k - FDIM)];
        Wg[i] = (__bf16)v;
    }
    if (i < FDIM * DDIM) Wout[i] = (__bf16)out_w[i];
    if (i < DDIM * FDIM) Wz[i]   = (__bf16)z_w[i];
    if (i < NG)          bg[i]   = b_ih[i] + b_hh[i];
}

// ---------------- preamble MLP ----------------
template<int K, int N, int ACT>
__global__ void rowmlp(const float* __restrict__ x, const float* __restrict__ W,
                       const float* __restrict__ bias, float* __restrict__ y)
{
    __shared__ float xr[K];
    int m = blockIdx.x;
    for (int k = threadIdx.x; k < K; k += blockDim.x) xr[k] = x[(size_t)m * K + k];
    __syncthreads();
    for (int n = threadIdx.x; n < N; n += blockDim.x) {
        const float* wr = W + (size_t)n * K;
        float s = bias[n];
        #pragma unroll 8
        for (int k = 0; k < K; ++k) s += xr[k] * wr[k];
        if (ACT) s = gelu_erf(s);
        y[(size_t)m * N + n] = s;
    }
}

// ---------------- persistent RNN scan: 1 WG/CU (512 thr, 8 waves), 16 rows ----------------
// A-frag LDS block layout: element (r,k) at byte ((k>>3)*16 + r)*16 + (k&7)*2.
// Wave wv owns 8 gate tiles (q>>1)*16 + 2*wv + (q&1) -> lane-local i,f,g,o.
// Gates: all 12 kt B-batches streamed from L2 with plain register loads through a
// 3-slot WITHIN-PHASE register pipeline (no load live-range crosses any barrier;
// full-drain __syncthreads only -- the R1/R2-proven L2-residency idiom).
// Tail: Wout+Wz LDS-resident (128 KB) -> out/z phases are global-load-free.
__global__ __launch_bounds__(512, 2)
void rnn_main(const float* __restrict__ eps,
              const __bf16* __restrict__ Wg, const float* __restrict__ bg,
              const __bf16* __restrict__ Wout, const float* __restrict__ ob,
              const __bf16* __restrict__ Wz, const float* __restrict__ zb,
              const float* __restrict__ x0, const float* __restrict__ h0,
              float* __restrict__ out)
{
    extern __shared__ __align__(16) char smem[];
    __bf16* xbuf  = (__bf16*)smem;            // 4 KB   x: 4 kt-blocks
    __bf16* hbufA = (__bf16*)(smem + 4096);   // 8 KB   h double-buffer
    __bf16* hbufB = (__bf16*)(smem + 12288);  // 8 KB
    __bf16* gbuf  = (__bf16*)(smem + 20480);  // 4 KB   gelu(out)
    char*   woutL = smem + 24576;             // 64 KB  Wout: [(wv*8+kt)*64 + lane]*16
    char*   wzL   = smem + 90112;             // 64 KB  Wz:   [(tile*4+kt)*64 + lane]*16

    const int tid  = threadIdx.x;
    const int wv   = tid >> 6;      // wave 0..7
    const int lane = tid & 63;
    const int lo   = lane & 15;
    const int hi   = lane >> 4;
    const int row0 = blockIdx.x * 16;
    const int abase = (hi * 16 + lo) * 16;    // A-frag byte offset within kt-block

    // ---- init activations ----
    for (int e = tid; e < 16 * 128; e += 512) {
        int r = e >> 7, k = e & 127;
        xbuf[(((k >> 3) << 4) + r) * 8 + (k & 7)] = (__bf16)x0[(size_t)(row0 + r) * 128 + k];
    }
    for (int e = tid; e < 16 * 256; e += 512) {
        int r = e >> 8, k = e & 255;
        hbufA[(((k >> 3) << 4) + r) * 8 + (k & 7)] = (__bf16)h0[(size_t)(row0 + r) * 256 + k];
    }
    // c state in D-frag layout: rows hi*4+j, cols d=(2*wv+p)*16+lo
    float c[2][4];
    #pragma unroll
    for (int p = 0; p < 2; ++p)
        #pragma unroll
        for (int j = 0; j < 4; ++j)
            c[p][j] = tanh_(h0[(size_t)(row0 + hi * 4 + j) * 256 + (2 * wv + p) * 16 + lo]);

    // ---- per-q weight row base pointers + biases ----
    const __bf16* wgbase[8];
    float biasq[8];
    #pragma unroll
    for (int q = 0; q < 8; ++q) {
        int tile = (q >> 1) * 16 + 2 * wv + (q & 1);
        wgbase[q] = Wg + (size_t)(tile * 16 + lo) * KG + hi * 8;
        biasq[q]  = bg[tile * 16 + lo];
    }
    const float bo  = ob[wv * 16 + lo];
    const float bmu = zb[wv * 16 + lo];
    const float bls = zb[128 + wv * 16 + lo];

    // ---- stage Wout + Wz into LDS (once) ----
    #pragma unroll
    for (int kt = 0; kt < 8; ++kt) {
        f32x4 v = *(const f32x4*)(Wout + (size_t)(wv * 16 + lo) * 256 + kt * 32 + hi * 8);
        *(f32x4*)(woutL + (size_t)((wv * 8 + kt) * 64 + lane) * 16) = v;
    }
    #pragma unroll
    for (int kt = 0; kt < 4; ++kt) {
        f32x4 v0 = *(const f32x4*)(Wz + (size_t)(wv * 16 + lo) * 128 + kt * 32 + hi * 8);
        f32x4 v1 = *(const f32x4*)(Wz + (size_t)((8 + wv) * 16 + lo) * 128 + kt * 32 + hi * 8);
        *(f32x4*)(wzL + (size_t)((wv * 4 + kt) * 64 + lane) * 16)       = v0;
        *(f32x4*)(wzL + (size_t)(((8 + wv) * 4 + kt) * 64 + lane) * 16) = v1;
    }

    __syncthreads();

    __bf16* hc = hbufA;
    __bf16* hn = hbufB;

    #define LOADB(SLOT, KT)                                               \
        _Pragma("unroll")                                                 \
        for (int q = 0; q < 8; ++q)                                       \
            Bb[SLOT][q] = *(const f32x4*)(wgbase[q] + (KT) * 32);

    for (int t = 0; t < SEQ; ++t) {
        // eps loads issued first; consumed at step end
        float ev[4];
        #pragma unroll
        for (int j = 0; j < 4; ++j)
            ev[j] = eps[((size_t)t * BATCH + row0 + hi * 4 + j) * 128 + wv * 16 + lo];

        // ---- gates = [x|h] @ Wg^T + b : 3-slot within-phase register pipeline ----
        f32x4 acc[8];
        #pragma unroll
        for (int q = 0; q < 8; ++q) acc[q] = (f32x4){biasq[q], biasq[q], biasq[q], biasq[q]};

        f32x4 Bb[3][8];
        LOADB(0, 0);
        LOADB(1, 1);
        LOADB(2, 2);

        #pragma unroll
        for (int kt = 0; kt < 12; ++kt) {
            const char* aptr = (kt < 4) ? ((const char*)xbuf + kt * 1024)
                                        : ((const char*)hc + (kt - 4) * 1024);
            bf16x8 a = *(const bf16x8*)(aptr + abase);
            const int s = kt % 3;
            #pragma unroll
            for (int q = 0; q < 8; ++q)
                acc[q] = mfma16(a, __builtin_bit_cast(bf16x8, Bb[s][q]), acc[q]);
            if (kt < 9) {              // refill just-consumed slot with batch kt+3
                LOADB(s, kt + 3);
            }
        }

        // ---- lane-local LSTM cell (acc order: i0 i1 f0 f1 g0 g1 o0 o1) ----
        #pragma unroll
        for (int p = 0; p < 2; ++p)
            #pragma unroll
            for (int j = 0; j < 4; ++j) {
                float iv = sigmoid_(acc[0 + p][j]);
                float fv = sigmoid_(acc[2 + p][j]);
                float gv = tanh_(acc[4 + p][j]);
                float ov = sigmoid_(acc[6 + p][j]);
                float cn = fv * c[p][j] + iv * gv;
                c[p][j] = cn;
                float hv = ov * tanh_(cn);
                int d = (2 * wv + p) * 16 + lo, r = hi * 4 + j;
                hn[(((d >> 3) << 4) + r) * 8 + (d & 7)] = (__bf16)hv;
            }
        __syncthreads();   // (1) new h visible (all weight loads already drained here)

        // ---- out = h @ Wout^T + ob (B from LDS: load-free tail) ----
        f32x4 ao0 = (f32x4){bo, bo, bo, bo};
        f32x4 ao1 = (f32x4){0.f, 0.f, 0.f, 0.f};
        #pragma unroll
        for (int kt = 0; kt < 8; ++kt) {
            bf16x8 a = *(const bf16x8*)((const char*)hn + kt * 1024 + abase);
            bf16x8 b = *(const bf16x8*)(woutL + (size_t)((wv * 8 + kt) * 64 + lane) * 16);
            if (kt & 1) ao1 = mfma16(a, b, ao1);
            else        ao0 = mfma16(a, b, ao0);
        }
        #pragma unroll
        for (int j = 0; j < 4; ++j) {
            int d = wv * 16 + lo, r = hi * 4 + j;
            gbuf[(((d >> 3) << 4) + r) * 8 + (d & 7)] = (__bf16)gelu_erf(ao0[j] + ao1[j]);
        }
        __syncthreads();   // (2) gelu(out) visible

        // ---- z = gelu(out) @ Wz^T + zb (B from LDS) ----
        f32x4 amu = (f32x4){bmu, bmu, bmu, bmu};
        f32x4 als = (f32x4){bls, bls, bls, bls};
        #pragma unroll
        for (int kt = 0; kt < 4; ++kt) {
            bf16x8 a  = *(const bf16x8*)((const char*)gbuf + kt * 1024 + abase);
            bf16x8 b0 = *(const bf16x8*)(wzL + (size_t)((wv * 4 + kt) * 64 + lane) * 16);
            bf16x8 b1 = *(const bf16x8*)(wzL + (size_t)(((8 + wv) * 4 + kt) * 64 + lane) * 16);
            amu = mfma16(a, b0, amu);
            als = mfma16(a, b1, als);
        }
        #pragma unroll
        for (int j = 0; j < 4; ++j) {
            float smp = amu[j] + __expf(als[j]) * ev[j];
            int d = wv * 16 + lo, r = hi * 4 + j;
            xbuf[(((d >> 3) << 4) + r) * 8 + (d & 7)] = (__bf16)smp;
            out[(size_t)(row0 + r) * (SEQ * 128) + (size_t)t * 128 + d] = smp;
        }
        __syncthreads();   // (3) xbuf ready for next step

        __bf16* tmp = hc; hc = hn; hn = tmp;
    }
    #undef LOADB
}

// ---------------- launch ----------------
extern "C" void kernel_launch(void* const* d_in, const int* in_sizes, int n_in,
                              void* d_out, int out_size, void* d_ws, size_t ws_size,
                              hipStream_t stream)
{
    const float* noise = (const float*)d_in[0];
    const float* eps   = (const float*)d_in[1];
    const float* w1 = (const float*)d_in[2];  const float* b1 = (const float*)d_in[3];
    const float* w2 = (const float*)d_in[4];  const float* b2 = (const float*)d_in[5];
    const float* w3 = (const float*)d_in[6];  const float* b3 = (const float*)d_in[7];
    const float* hw = (const float*)d_in[8];  const float* hb = (const float*)d_in[9];
    const float* wih = (const float*)d_in[10]; const float* bih = (const float*)d_in[11];
    const float* whh = (const float*)d_in[12]; const float* bhh = (const float*)d_in[13];
    const float* ow = (const float*)d_in[14]; const float* ob = (const float*)d_in[15];
    const float* zw = (const float*)d_in[16]; const float* zb = (const float*)d_in[17];
    float* out = (float*)d_out;

    char* ws = (char*)d_ws;
    __bf16* Wg   = (__bf16*)(ws);                         // 786432 B
    __bf16* Wout = (__bf16*)(ws + 786432);                // 65536 B
    __bf16* Wz   = (__bf16*)(ws + 851968);                // 65536 B
    float*  bg   = (float*) (ws + 917504);                // 4096 B
    float*  t0   = (float*) (ws + 921600);                // 2 MiB
    float*  t1   = (float*) (ws + 921600 + 2097152);      // 2 MiB
    float*  hid  = (float*) (ws + 921600 + 2 * 2097152);  // 4 MiB

    prep_weights<<<1536, 256, 0, stream>>>(wih, whh, bih, bhh, ow, zw, Wg, Wout, Wz, bg);

    rowmlp<128, 128, 1><<<4096, 128, 0, stream>>>(noise, w1, b1, t0);
    rowmlp<128, 128, 1><<<4096, 128, 0, stream>>>(t0, w2, b2, t1);
    rowmlp<128, 128, 0><<<4096, 128, 0, stream>>>(t1, w3, b3, t0);   // inputs
    rowmlp<128, 256, 0><<<4096, 256, 0, stream>>>(t0, hw, hb, hid);  // hidden

    // dynamic LDS: 24576 B activations + 131072 B resident Wout/Wz
    rnn_main<<<256, 512, 155648, stream>>>(eps, Wg, bg, Wout, ob, Wz, zb, t0, hid, out);
}